// Round 5
// baseline (172.228 us; speedup 1.0000x reference)
//
#include <hip/hip_runtime.h>
#include <math.h>

#define N_ 6
#define C_ 256
#define H_ 180
#define W_ 320
#define HW_ (H_*W_)
#define P_ 25600        // 40*40*16, p = (ix*40+iy)*16+iz
#define Q_ 1600         // 40*40 z-columns; p = q*16+iz
#define DH_ 360
#define DW_ 640

typedef float floatx4 __attribute__((ext_vector_type(4)));

// jax.image.resize linear+antialias, scale=1/2: output i samples input coord 2i+0.5,
// triangle kernel scaled by 2 -> taps {2i-1..2i+2}, raw weights {.25,.75,.75,.25},
// renormalized after dropping out-of-range taps (edges: /1.75 instead of /2).
__device__ __forceinline__ void resize_taps(int i, int m_in, int idx[4], float w[4]) {
    const float kv0 = 0.25f, kv1 = 0.75f;
    int j0 = 2*i - 1;
    float s = 0.f;
    #pragma unroll
    for (int t = 0; t < 4; ++t) {
        int j = j0 + t;
        bool ok = (j >= 0) && (j < m_in);
        idx[t] = ok ? j : 0;
        float kv = (t == 0 || t == 3) ? kv0 : kv1;
        w[t] = ok ? kv : 0.f;
        s = __fadd_rn(s, w[t]);
    }
    #pragma unroll
    for (int t = 0; t < 4; ++t) w[t] = __fdiv_rn(w[t], s);
}

__global__ void prep_kernel(const float* __restrict__ points,
                            const float* __restrict__ proj,
                            const float* __restrict__ depth,
                            const float* __restrict__ offsets,
                            float* __restrict__ valid_out,
                            float* __restrict__ pts3d_out,
                            int*   __restrict__ linflag) {
    int idx = blockIdx.x * blockDim.x + threadIdx.x;
    if (idx >= N_*P_) return;
    int n = idx / P_;
    int p = idx - n*P_;

    float X = points[p];
    float Y = points[P_ + p];
    float Z = points[2*P_ + p];

    const float* K = proj + n*12;
    // einsum dot, sequential f32, no fma contraction
    float p0 = __fadd_rn(__fadd_rn(__fadd_rn(__fmul_rn(K[0],X), __fmul_rn(K[1],Y)), __fmul_rn(K[2],Z)), K[3]);
    float p1 = __fadd_rn(__fadd_rn(__fadd_rn(__fmul_rn(K[4],X), __fmul_rn(K[5],Y)), __fmul_rn(K[6],Z)), K[7]);
    float z  = __fadd_rn(__fadd_rn(__fadd_rn(__fmul_rn(K[8],X), __fmul_rn(K[9],Y)), __fmul_rn(K[10],Z)), K[11]);

    float o0 = __fmul_rn(tanhf(offsets[2*p]),     5.0f);
    float o1 = __fmul_rn(tanhf(offsets[2*p + 1]), 5.0f);

    float x = __fadd_rn(__fdiv_rn(p0, z), o0);
    float y = __fadd_rn(__fdiv_rn(p1, z), o1);

    int xi = (int)rintf(x);   // rintf = round half to even = jnp.round
    int yi = (int)rintf(y);

    bool valid = (xi >= 0) && (yi >= 0) && (xi < W_) && (yi < H_) && (z > 0.f);

    int xc = min(max(xi, 0), W_-1);
    int yc = min(max(yi, 0), H_-1);

    int ri[4], ci[4];
    float rw[4], cw[4];
    resize_taps(yc, DH_, ri, rw);
    resize_taps(xc, DW_, ci, cw);

    const float* dbase = depth + (size_t)n * (DH_*DW_);
    // H-contraction first, then W, each sequential f32 (matches weight-matrix einsum)
    float dg = 0.f;
    #pragma unroll
    for (int t = 0; t < 4; ++t) {
        int c = ci[t];
        float acc = 0.f;
        #pragma unroll
        for (int u = 0; u < 4; ++u) {
            acc = __fadd_rn(acc, __fmul_rn(rw[u], dbase[ri[u]*DW_ + c]));
        }
        dg = __fadd_rn(dg, __fmul_rn(cw[t], acc));
    }

    valid = valid && (z > __fsub_rn(dg, 0.5f)) && (z < __fadd_rn(dg, 0.5f));

    int lin = yc*W_ + xc;
    float vm = valid ? 1.0f : 0.0f;

    valid_out[idx] = vm;
    float* p3 = pts3d_out + (size_t)n * (3*P_);
    p3[p]        = X * vm;
    p3[P_ + p]   = Y * vm;
    p3[2*P_ + p] = Z * vm;
    linflag[idx] = valid ? lin : -1;
}

// Thread = one z-column (16 z) of one (n,c):
//  - 4 coalesced int4 linflag loads (64B/thread, wave = 4KB contiguous, L2-resident)
//  - 16 INDEPENDENT predicated gathers in flight (4x the MLP of previous rounds)
//  - stores: 16 z = exactly one 64B volume line per thread; consecutive threads =
//    consecutive lines -> wave writes 4KB fully contiguous, nontemporal.
__global__ void __launch_bounds__(256)
fill_kernel(const float* __restrict__ feat,
            const int*   __restrict__ linflag,
            float* __restrict__ vol) {
    int tid = blockIdx.x * 256 + threadIdx.x;      // over N_*C_*Q_, exact
    int q    = tid % Q_;
    int rest = tid / Q_;
    int c = rest % C_;
    int n = rest / C_;

    const int4* lfp = reinterpret_cast<const int4*>(linflag + n*P_ + q*16);
    int4 lf0 = lfp[0];
    int4 lf1 = lfp[1];
    int4 lf2 = lfp[2];
    int4 lf3 = lfp[3];

    const float* fb = feat + (size_t)(n*C_ + c) * HW_;

    float v0  = (lf0.x >= 0) ? fb[lf0.x] : 0.f;
    float v1  = (lf0.y >= 0) ? fb[lf0.y] : 0.f;
    float v2  = (lf0.z >= 0) ? fb[lf0.z] : 0.f;
    float v3  = (lf0.w >= 0) ? fb[lf0.w] : 0.f;
    float v4  = (lf1.x >= 0) ? fb[lf1.x] : 0.f;
    float v5  = (lf1.y >= 0) ? fb[lf1.y] : 0.f;
    float v6  = (lf1.z >= 0) ? fb[lf1.z] : 0.f;
    float v7  = (lf1.w >= 0) ? fb[lf1.w] : 0.f;
    float v8  = (lf2.x >= 0) ? fb[lf2.x] : 0.f;
    float v9  = (lf2.y >= 0) ? fb[lf2.y] : 0.f;
    float v10 = (lf2.z >= 0) ? fb[lf2.z] : 0.f;
    float v11 = (lf2.w >= 0) ? fb[lf2.w] : 0.f;
    float v12 = (lf3.x >= 0) ? fb[lf3.x] : 0.f;
    float v13 = (lf3.y >= 0) ? fb[lf3.y] : 0.f;
    float v14 = (lf3.z >= 0) ? fb[lf3.z] : 0.f;
    float v15 = (lf3.w >= 0) ? fb[lf3.w] : 0.f;

    float* dst = vol + (size_t)(n*C_ + c) * P_ + q*16;
    floatx4 a = {v0,  v1,  v2,  v3};
    floatx4 b = {v4,  v5,  v6,  v7};
    floatx4 d = {v8,  v9,  v10, v11};
    floatx4 e = {v12, v13, v14, v15};
    __builtin_nontemporal_store(a, reinterpret_cast<floatx4*>(dst));
    __builtin_nontemporal_store(b, reinterpret_cast<floatx4*>(dst + 4));
    __builtin_nontemporal_store(d, reinterpret_cast<floatx4*>(dst + 8));
    __builtin_nontemporal_store(e, reinterpret_cast<floatx4*>(dst + 12));
}

extern "C" void kernel_launch(void* const* d_in, const int* in_sizes, int n_in,
                              void* d_out, int out_size, void* d_ws, size_t ws_size,
                              hipStream_t stream) {
    const float* features = (const float*)d_in[0];   // (6,256,180,320)
    const float* points   = (const float*)d_in[1];   // (3,40,40,16)
    const float* proj     = (const float*)d_in[2];   // (6,3,4)
    const float* depth    = (const float*)d_in[3];   // (6,360,640)
    const float* offsets  = (const float*)d_in[4];   // (1,25600,2)

    float* out = (float*)d_out;
    float* vol       = out;                                  // 6*256*25600
    float* valid_out = out + (size_t)N_*C_*P_;               // 6*25600
    float* pts3d_out = valid_out + (size_t)N_*P_;            // 6*3*25600

    int* linflag = (int*)d_ws;                               // 6*25600 ints

    {
        int total = N_*P_;
        int blocks = (total + 255) / 256;
        prep_kernel<<<blocks, 256, 0, stream>>>(points, proj, depth, offsets,
                                                valid_out, pts3d_out, linflag);
    }
    {
        int total = N_*C_*Q_;            // 2,457,600 — divisible by 256
        int blocks = total / 256;        // 9600
        fill_kernel<<<blocks, 256, 0, stream>>>(features, linflag, vol);
    }
}

// Round 6
// 56.917 us; speedup vs baseline: 3.0259x; 3.0259x over previous
//
#include <hip/hip_runtime.h>
#include <math.h>

#define N_ 6
#define C_ 256
#define H_ 180
#define W_ 320
#define HW_ (H_*W_)
#define P_ 25600        // 40*40*16, p = (ix*40+iy)*16+iz
#define P4_ (P_/4)      // 6400
#define DH_ 360
#define DW_ 640
#define NXCD_ 8
#define SLOTS_ 25       // blocks per (n,c) plane: 6400 p4-groups / 256 threads

typedef float floatx4 __attribute__((ext_vector_type(4)));

// jax.image.resize linear+antialias, scale=1/2: output i samples input coord 2i+0.5,
// triangle kernel scaled by 2 -> taps {2i-1..2i+2}, raw weights {.25,.75,.75,.25},
// renormalized after dropping out-of-range taps (edges: /1.75 instead of /2).
__device__ __forceinline__ void resize_taps(int i, int m_in, int idx[4], float w[4]) {
    const float kv0 = 0.25f, kv1 = 0.75f;
    int j0 = 2*i - 1;
    float s = 0.f;
    #pragma unroll
    for (int t = 0; t < 4; ++t) {
        int j = j0 + t;
        bool ok = (j >= 0) && (j < m_in);
        idx[t] = ok ? j : 0;
        float kv = (t == 0 || t == 3) ? kv0 : kv1;
        w[t] = ok ? kv : 0.f;
        s = __fadd_rn(s, w[t]);
    }
    #pragma unroll
    for (int t = 0; t < 4; ++t) w[t] = __fdiv_rn(w[t], s);
}

__global__ void prep_kernel(const float* __restrict__ points,
                            const float* __restrict__ proj,
                            const float* __restrict__ depth,
                            const float* __restrict__ offsets,
                            float* __restrict__ valid_out,
                            float* __restrict__ pts3d_out,
                            int*   __restrict__ linflag) {
    int idx = blockIdx.x * blockDim.x + threadIdx.x;
    if (idx >= N_*P_) return;
    int n = idx / P_;
    int p = idx - n*P_;

    float X = points[p];
    float Y = points[P_ + p];
    float Z = points[2*P_ + p];

    const float* K = proj + n*12;
    // einsum dot, sequential f32, no fma contraction
    float p0 = __fadd_rn(__fadd_rn(__fadd_rn(__fmul_rn(K[0],X), __fmul_rn(K[1],Y)), __fmul_rn(K[2],Z)), K[3]);
    float p1 = __fadd_rn(__fadd_rn(__fadd_rn(__fmul_rn(K[4],X), __fmul_rn(K[5],Y)), __fmul_rn(K[6],Z)), K[7]);
    float z  = __fadd_rn(__fadd_rn(__fadd_rn(__fmul_rn(K[8],X), __fmul_rn(K[9],Y)), __fmul_rn(K[10],Z)), K[11]);

    float o0 = __fmul_rn(tanhf(offsets[2*p]),     5.0f);
    float o1 = __fmul_rn(tanhf(offsets[2*p + 1]), 5.0f);

    float x = __fadd_rn(__fdiv_rn(p0, z), o0);
    float y = __fadd_rn(__fdiv_rn(p1, z), o1);

    int xi = (int)rintf(x);   // rintf = round half to even = jnp.round
    int yi = (int)rintf(y);

    bool valid = (xi >= 0) && (yi >= 0) && (xi < W_) && (yi < H_) && (z > 0.f);

    int xc = min(max(xi, 0), W_-1);
    int yc = min(max(yi, 0), H_-1);

    int ri[4], ci[4];
    float rw[4], cw[4];
    resize_taps(yc, DH_, ri, rw);
    resize_taps(xc, DW_, ci, cw);

    const float* dbase = depth + (size_t)n * (DH_*DW_);
    // H-contraction first, then W, each sequential f32 (matches weight-matrix einsum)
    float dg = 0.f;
    #pragma unroll
    for (int t = 0; t < 4; ++t) {
        int c = ci[t];
        float acc = 0.f;
        #pragma unroll
        for (int u = 0; u < 4; ++u) {
            acc = __fadd_rn(acc, __fmul_rn(rw[u], dbase[ri[u]*DW_ + c]));
        }
        dg = __fadd_rn(dg, __fmul_rn(cw[t], acc));
    }

    valid = valid && (z > __fsub_rn(dg, 0.5f)) && (z < __fadd_rn(dg, 0.5f));

    int lin = yc*W_ + xc;
    float vm = valid ? 1.0f : 0.0f;

    valid_out[idx] = vm;
    float* p3 = pts3d_out + (size_t)n * (3*P_);
    p3[p]        = X * vm;
    p3[P_ + p]   = Y * vm;
    p3[2*P_ + p] = Z * vm;
    linflag[idx] = valid ? lin : -1;
}

// R1 fill structure (4 points/thread, 25 blocks per (n,c) plane, dense NT float4
// stores) + XCD-aware swizzle: consecutive hw blocks round-robin XCDs, so map
// blockIdx -> (xcd = B%8) and give each XCD every-8th plane, with all 25 blocks
// of one plane on the SAME xcd. A plane's gathered feature lines are then fetched
// into one L2 once and reused, instead of duplicated across up to 8 XCD L2s.
__global__ void __launch_bounds__(256)
fill_kernel(const float* __restrict__ feat,
            const int*   __restrict__ linflag,
            float* __restrict__ vol) {
    int B = blockIdx.x;                   // 38400 = 8 xcd * 192 plane_local * 25 slots
    int xcd = B & 7;
    int i = B >> 3;                       // 0..4799
    int plane_local = i / SLOTS_;         // 0..191
    int slot = i - plane_local*SLOTS_;    // 0..24
    int plane = plane_local*NXCD_ + xcd;  // 0..1535 == n*C_ + c
    int n = plane >> 8;
    int c = plane & 255;
    int p4 = slot*256 + threadIdx.x;      // 0..6399

    const int4 lf = *reinterpret_cast<const int4*>(linflag + n*P_ + p4*4);
    const float* fb = feat + (size_t)plane * HW_;

    floatx4 v;
    v.x = (lf.x >= 0) ? fb[lf.x] : 0.f;
    v.y = (lf.y >= 0) ? fb[lf.y] : 0.f;
    v.z = (lf.z >= 0) ? fb[lf.z] : 0.f;
    v.w = (lf.w >= 0) ? fb[lf.w] : 0.f;
    __builtin_nontemporal_store(v, reinterpret_cast<floatx4*>(vol + (size_t)plane * P_ + p4*4));
}

extern "C" void kernel_launch(void* const* d_in, const int* in_sizes, int n_in,
                              void* d_out, int out_size, void* d_ws, size_t ws_size,
                              hipStream_t stream) {
    const float* features = (const float*)d_in[0];   // (6,256,180,320)
    const float* points   = (const float*)d_in[1];   // (3,40,40,16)
    const float* proj     = (const float*)d_in[2];   // (6,3,4)
    const float* depth    = (const float*)d_in[3];   // (6,360,640)
    const float* offsets  = (const float*)d_in[4];   // (1,25600,2)

    float* out = (float*)d_out;
    float* vol       = out;                                  // 6*256*25600
    float* valid_out = out + (size_t)N_*C_*P_;               // 6*25600
    float* pts3d_out = valid_out + (size_t)N_*P_;            // 6*3*25600

    int* linflag = (int*)d_ws;                               // 6*25600 ints

    {
        int total = N_*P_;
        int blocks = (total + 255) / 256;
        prep_kernel<<<blocks, 256, 0, stream>>>(points, proj, depth, offsets,
                                                valid_out, pts3d_out, linflag);
    }
    {
        int blocks = NXCD_ * (N_*C_/NXCD_) * SLOTS_;   // 38400
        fill_kernel<<<blocks, 256, 0, stream>>>(features, linflag, vol);
    }
}